// Round 1
// baseline (621.419 us; speedup 1.0000x reference)
//
#include <hip/hip_runtime.h>

#define F_IN  512
#define H_DIM 16
#define C_OUT 40

static inline size_t align_up(size_t x, size_t a) { return (x + a - 1) / a * a; }

// ---- degree histograms -----------------------------------------------------
__global__ void k_degrees(const int* __restrict__ src, const int* __restrict__ dst,
                          int* __restrict__ outdeg, int* __restrict__ indeg, int E) {
    int stride = gridDim.x * blockDim.x;
    for (int i = blockIdx.x * blockDim.x + threadIdx.x; i < E; i += stride) {
        atomicAdd(&outdeg[src[i]], 1);
        atomicAdd(&indeg[dst[i]], 1);
    }
}

// ---- 2-level exclusive scan (N=100000, 391 blocks <= 512) ------------------
__global__ void k_scan1(const int* __restrict__ in, int* __restrict__ out,
                        int* __restrict__ bsums, int n) {
    __shared__ int tmp[256];
    int t = threadIdx.x;
    int gid = blockIdx.x * 256 + t;
    int v = (gid < n) ? in[gid] : 0;
    tmp[t] = v;
    __syncthreads();
    for (int off = 1; off < 256; off <<= 1) {
        int add = (t >= off) ? tmp[t - off] : 0;
        __syncthreads();
        tmp[t] += add;
        __syncthreads();
    }
    if (gid < n) out[gid] = tmp[t] - v;   // exclusive
    if (t == 255) bsums[blockIdx.x] = tmp[255];
}

__global__ void k_scan2(int* bsums, int nb) {
    __shared__ int tmp[512];
    int t = threadIdx.x;
    int v = (t < nb) ? bsums[t] : 0;
    tmp[t] = v;
    __syncthreads();
    for (int off = 1; off < 512; off <<= 1) {
        int add = (t >= off) ? tmp[t - off] : 0;
        __syncthreads();
        tmp[t] += add;
        __syncthreads();
    }
    if (t < nb) bsums[t] = tmp[t] - v;    // exclusive block offsets
}

__global__ void k_scan3(int* __restrict__ out, const int* __restrict__ bsums, int n) {
    int gid = blockIdx.x * 256 + threadIdx.x;
    if (gid < n) out[gid] += bsums[blockIdx.x];
}

// ---- bin edges into CSR-by-dst ---------------------------------------------
__global__ void k_bin(const int* __restrict__ src, const int* __restrict__ dst,
                      const int* __restrict__ csroff, int* __restrict__ cnt,
                      int* __restrict__ csrsrc, int E) {
    int stride = gridDim.x * blockDim.x;
    for (int i = blockIdx.x * blockDim.x + threadIdx.x; i < E; i += stride) {
        int d = dst[i];
        int pos = csroff[d] + atomicAdd(&cnt[d], 1);
        csrsrc[pos] = src[i];
    }
}

// ---- GEMM1: h1[row] = norm_src(row) * (x[row] @ W1) ------------------------
__global__ __launch_bounds__(256) void k_gemm1(const float* __restrict__ x,
        const float* __restrict__ W1, const int* __restrict__ outdeg,
        float* __restrict__ h1, int n) {
    __shared__ float Ws[F_IN * H_DIM];           // 32 KB
    for (int i = threadIdx.x; i < F_IN * H_DIM / 4; i += 256)
        ((float4*)Ws)[i] = ((const float4*)W1)[i];
    __syncthreads();

    int row = blockIdx.x * 256 + threadIdx.x;
    if (row >= n) return;
    const float4* xr = (const float4*)(x + (size_t)row * F_IN);

    float acc[H_DIM];
#pragma unroll
    for (int j = 0; j < H_DIM; ++j) acc[j] = 0.f;

    for (int c = 0; c < F_IN / 16; ++c) {        // 32 chunks of 16 k (64B/lane)
        float4 xv0 = xr[c * 4 + 0];
        float4 xv1 = xr[c * 4 + 1];
        float4 xv2 = xr[c * 4 + 2];
        float4 xv3 = xr[c * 4 + 3];
        float xs[16] = {xv0.x, xv0.y, xv0.z, xv0.w,
                        xv1.x, xv1.y, xv1.z, xv1.w,
                        xv2.x, xv2.y, xv2.z, xv2.w,
                        xv3.x, xv3.y, xv3.z, xv3.w};
#pragma unroll
        for (int kk = 0; kk < 16; ++kk) {
            const float* wr = &Ws[(c * 16 + kk) * H_DIM];
#pragma unroll
            for (int j = 0; j < H_DIM; ++j) acc[j] += xs[kk] * wr[j];
        }
    }

    float ns = rsqrtf(fmaxf((float)outdeg[row], 1.f));
    float4* o = (float4*)(h1 + (size_t)row * H_DIM);
#pragma unroll
    for (int qq = 0; qq < 4; ++qq)
        o[qq] = make_float4(acc[qq * 4 + 0] * ns, acc[qq * 4 + 1] * ns,
                            acc[qq * 4 + 2] * ns, acc[qq * 4 + 3] * ns);
}

// ---- agg1: g[v] = relu(norm_dst(v)*sum_{e in(v)} h1[src] + b1) * norm_src(v)
// 4 lanes per dst, float4 per lane (one 64B line per edge gather)
__global__ __launch_bounds__(256) void k_agg1(const int* __restrict__ csroff,
        const int* __restrict__ indeg, const int* __restrict__ outdeg,
        const int* __restrict__ csrsrc, const float* __restrict__ h1,
        const float* __restrict__ b1, float* __restrict__ g, int n) {
    int t = threadIdx.x;
    int q = t & 3;
    int lv = t >> 2;
    int v = blockIdx.x * 64 + lv;
    if (v >= n) return;
    int start = csroff[v];
    int len = indeg[v];
    const float4* h4 = (const float4*)h1;
    float4 acc = make_float4(0.f, 0.f, 0.f, 0.f);
    for (int i = 0; i < len; ++i) {
        int s = csrsrc[start + i];
        float4 m = h4[(size_t)s * 4 + q];
        acc.x += m.x; acc.y += m.y; acc.z += m.z; acc.w += m.w;
    }
    float nd = rsqrtf(fmaxf((float)len, 1.f));
    float ns = rsqrtf(fmaxf((float)outdeg[v], 1.f));
    float4 bb = ((const float4*)b1)[q];
    float4 r;
    r.x = fmaxf(acc.x * nd + bb.x, 0.f) * ns;
    r.y = fmaxf(acc.y * nd + bb.y, 0.f) * ns;
    r.z = fmaxf(acc.z * nd + bb.z, 0.f) * ns;
    r.w = fmaxf(acc.w * nd + bb.w, 0.f) * ns;
    ((float4*)g)[(size_t)v * 4 + q] = r;
}

// ---- agg2 + GEMM2: out[v] = norm_dst(v) * (sum g[src]) @ W2 + b2 -----------
__global__ __launch_bounds__(256) void k_agg2(const int* __restrict__ csroff,
        const int* __restrict__ indeg, const int* __restrict__ csrsrc,
        const float* __restrict__ gbuf, const float* __restrict__ W2,
        const float* __restrict__ b2, float* __restrict__ out, int n) {
    __shared__ float Ws[H_DIM * C_OUT];     // 2.56 KB
    __shared__ float agg[64][17];           // pad 17: 2-way max on read phase
    int t = threadIdx.x;
    for (int i = t; i < H_DIM * C_OUT; i += 256) Ws[i] = W2[i];

    int q = t & 3;
    int lv = t >> 2;
    int v = blockIdx.x * 64 + lv;
    float4 acc = make_float4(0.f, 0.f, 0.f, 0.f);
    if (v < n) {
        int start = csroff[v];
        int len = indeg[v];
        const float4* g4 = (const float4*)gbuf;
        for (int i = 0; i < len; ++i) {
            int s = csrsrc[start + i];
            float4 m = g4[(size_t)s * 4 + q];
            acc.x += m.x; acc.y += m.y; acc.z += m.z; acc.w += m.w;
        }
    }
    agg[lv][q * 4 + 0] = acc.x;
    agg[lv][q * 4 + 1] = acc.y;
    agg[lv][q * 4 + 2] = acc.z;
    agg[lv][q * 4 + 3] = acc.w;
    __syncthreads();

    // 64 dst * 40 outputs = 2560 outputs; 10 per thread, coalesced writes
    for (int idx = t; idx < 64 * C_OUT; idx += 256) {
        int dlv = idx / C_OUT;
        int c = idx % C_OUT;
        int dv = blockIdx.x * 64 + dlv;
        if (dv < n) {
            float s = 0.f;
#pragma unroll
            for (int k = 0; k < H_DIM; ++k) s += agg[dlv][k] * Ws[k * C_OUT + c];
            float nd = rsqrtf(fmaxf((float)indeg[dv], 1.f));
            out[(size_t)dv * C_OUT + c] = s * nd + b2[c];
        }
    }
}

extern "C" void kernel_launch(void* const* d_in, const int* in_sizes, int n_in,
                              void* d_out, int out_size, void* d_ws, size_t ws_size,
                              hipStream_t stream) {
    const float* x  = (const float*)d_in[0];
    const int* esrc = (const int*)d_in[1];
    const int* edst = (const int*)d_in[2];
    const float* W1 = (const float*)d_in[3];
    const float* b1 = (const float*)d_in[4];
    const float* W2 = (const float*)d_in[5];
    const float* b2 = (const float*)d_in[6];
    float* out = (float*)d_out;

    const int N = in_sizes[0] / F_IN;   // 100000
    const int E = in_sizes[1];          // 3200000

    char* p = (char*)d_ws;
    auto alloc = [&](size_t bytes) -> char* {
        char* r = p; p += align_up(bytes, 256); return r;
    };
    int*   outdeg = (int*)alloc((size_t)N * 4);
    int*   indeg  = (int*)alloc((size_t)N * 4);
    int*   csroff = (int*)alloc((size_t)N * 4);
    int*   cnt    = (int*)alloc((size_t)N * 4);
    int*   bsums  = (int*)alloc(512 * 4);
    int*   csrsrc = (int*)alloc((size_t)E * 4);
    float* h1     = (float*)alloc((size_t)N * H_DIM * 4);
    float* g      = (float*)alloc((size_t)N * H_DIM * 4);

    hipMemsetAsync(outdeg, 0, (size_t)N * 4, stream);
    hipMemsetAsync(indeg,  0, (size_t)N * 4, stream);
    hipMemsetAsync(cnt,    0, (size_t)N * 4, stream);

    k_degrees<<<2048, 256, 0, stream>>>(esrc, edst, outdeg, indeg, E);

    int nb = (N + 255) / 256;           // 391 <= 512
    k_scan1<<<nb, 256, 0, stream>>>(indeg, csroff, bsums, N);
    k_scan2<<<1, 512, 0, stream>>>(bsums, nb);
    k_scan3<<<nb, 256, 0, stream>>>(csroff, bsums, N);

    k_bin<<<2048, 256, 0, stream>>>(esrc, edst, csroff, cnt, csrsrc, E);

    k_gemm1<<<(N + 255) / 256, 256, 0, stream>>>(x, W1, outdeg, h1, N);

    int nb64 = (N + 63) / 64;
    k_agg1<<<nb64, 256, 0, stream>>>(csroff, indeg, outdeg, csrsrc, h1, b1, g, N);
    k_agg2<<<nb64, 256, 0, stream>>>(csroff, indeg, csrsrc, g, W2, b2, out, N);
}

// Round 2
// 316.146 us; speedup vs baseline: 1.9656x; 1.9656x over previous
//
#include <hip/hip_runtime.h>

#define F_IN  512
#define H_DIM 16
#define C_OUT 40
#define NBLK_P 256          // partition blocks (phase A/C)

static inline size_t align_up(size_t x, size_t a) { return (x + a - 1) / a * a; }

// ---- partition phase A: per-block LDS histogram of key>>8 ------------------
__global__ __launch_bounds__(256) void k_pcount(const int* __restrict__ keys, int E,
        int chunk, int nbk, int* __restrict__ histT) {
    __shared__ int h[512];
    for (int i = threadIdx.x; i < nbk; i += 256) h[i] = 0;
    __syncthreads();
    int b = blockIdx.x;
    int s = b * chunk, e = min(s + chunk, E);
    for (int i = s + threadIdx.x; i < e; i += 256)
        atomicAdd(&h[keys[i] >> 8], 1);
    __syncthreads();
    for (int i = threadIdx.x; i < nbk; i += 256)
        histT[i * NBLK_P + b] = h[i];
}

// ---- 2-level exclusive scan ------------------------------------------------
__global__ void k_scan1(const int* __restrict__ in, int* __restrict__ out,
                        int* __restrict__ bsums, int n) {
    __shared__ int tmp[256];
    int t = threadIdx.x;
    int gid = blockIdx.x * 256 + t;
    int v = (gid < n) ? in[gid] : 0;
    tmp[t] = v;
    __syncthreads();
    for (int off = 1; off < 256; off <<= 1) {
        int add = (t >= off) ? tmp[t - off] : 0;
        __syncthreads();
        tmp[t] += add;
        __syncthreads();
    }
    if (gid < n) out[gid] = tmp[t] - v;   // exclusive
    if (t == 255) bsums[blockIdx.x] = tmp[255];
}

__global__ void k_scan2(int* bsums, int nb) {
    __shared__ int tmp[512];
    int t = threadIdx.x;
    int v = (t < nb) ? bsums[t] : 0;
    tmp[t] = v;
    __syncthreads();
    for (int off = 1; off < 512; off <<= 1) {
        int add = (t >= off) ? tmp[t - off] : 0;
        __syncthreads();
        tmp[t] += add;
        __syncthreads();
    }
    if (t < nb) bsums[t] = tmp[t] - v;    // exclusive block offsets
}

__global__ void k_scan3(int* __restrict__ out, const int* __restrict__ bsums, int n) {
    int gid = blockIdx.x * 256 + threadIdx.x;
    if (gid < n) out[gid] += bsums[blockIdx.x];
}

// ---- partition phase C: scatter into bucket-contiguous layout --------------
__global__ __launch_bounds__(256) void k_pscat_key(const int* __restrict__ keys, int E,
        int chunk, const int* __restrict__ histT, int* __restrict__ outk) {
    __shared__ int cnt[512];
    for (int i = threadIdx.x; i < 512; i += 256) cnt[i] = 0;
    __syncthreads();
    int b = blockIdx.x;
    int s = b * chunk, e = min(s + chunk, E);
    for (int i = s + threadIdx.x; i < e; i += 256) {
        int k = keys[i];
        int bk = k >> 8;
        int r = atomicAdd(&cnt[bk], 1);
        outk[histT[bk * NBLK_P + b] + r] = k;
    }
}

__global__ __launch_bounds__(256) void k_pscat_pair(const int* __restrict__ src,
        const int* __restrict__ dst, int E, int chunk,
        const int* __restrict__ histT, int2* __restrict__ outp) {
    __shared__ int cnt[512];
    for (int i = threadIdx.x; i < 512; i += 256) cnt[i] = 0;
    __syncthreads();
    int b = blockIdx.x;
    int s = b * chunk, e = min(s + chunk, E);
    for (int i = s + threadIdx.x; i < e; i += 256) {
        int d = dst[i];
        int bk = d >> 8;
        int r = atomicAdd(&cnt[bk], 1);
        outp[histT[bk * NBLK_P + b] + r] = make_int2(src[i], d);
    }
}

// ---- per-bucket degree count (outdeg from bucketed src keys) ---------------
__global__ __launch_bounds__(256) void k_bcount(const int* __restrict__ keysb,
        const int* __restrict__ histT, int nbk, int E, int N, int* __restrict__ deg) {
    __shared__ int h[256];
    int t = threadIdx.x, b = blockIdx.x;
    int bstart = histT[b * NBLK_P];
    int bend = (b + 1 < nbk) ? histT[(b + 1) * NBLK_P] : E;
    h[t] = 0;
    __syncthreads();
    for (int i = bstart + t; i < bend; i += 256)
        atomicAdd(&h[keysb[i] & 255], 1);
    __syncthreads();
    int node = (b << 8) + t;
    if (node < N) deg[node] = h[t];
}

// ---- per-bucket CSR build (indeg, csroff, csrsrc) — no global atomics ------
__global__ __launch_bounds__(256) void k_bbuild(const int2* __restrict__ pairsb,
        const int* __restrict__ histT, int nbk, int E, int N,
        int* __restrict__ indeg, int* __restrict__ csroff, int* __restrict__ csrsrc) {
    __shared__ int h[256], offs[256], cnt[256], tmp[256];
    int t = threadIdx.x, b = blockIdx.x;
    int bstart = histT[b * NBLK_P];
    int bend = (b + 1 < nbk) ? histT[(b + 1) * NBLK_P] : E;
    h[t] = 0; cnt[t] = 0;
    __syncthreads();
    for (int i = bstart + t; i < bend; i += 256)
        atomicAdd(&h[pairsb[i].y & 255], 1);
    __syncthreads();
    int v = h[t];
    tmp[t] = v;
    __syncthreads();
    for (int off = 1; off < 256; off <<= 1) {
        int add = (t >= off) ? tmp[t - off] : 0;
        __syncthreads();
        tmp[t] += add;
        __syncthreads();
    }
    offs[t] = tmp[t] - v;
    __syncthreads();
    int node = (b << 8) + t;
    if (node < N) {
        indeg[node] = v;
        csroff[node] = bstart + offs[t];
    }
    for (int i = bstart + t; i < bend; i += 256) {
        int2 p = pairsb[i];
        int l = p.y & 255;
        int r = atomicAdd(&cnt[l], 1);
        csrsrc[bstart + offs[l] + r] = p.x;
    }
}

// ---- GEMM1: h1[row] = norm_src(row) * (x[row] @ W1) ------------------------
__global__ __launch_bounds__(256) void k_gemm1(const float* __restrict__ x,
        const float* __restrict__ W1, const int* __restrict__ outdeg,
        float* __restrict__ h1, int n) {
    __shared__ float Ws[F_IN * H_DIM];           // 32 KB
    for (int i = threadIdx.x; i < F_IN * H_DIM / 4; i += 256)
        ((float4*)Ws)[i] = ((const float4*)W1)[i];
    __syncthreads();

    int row = blockIdx.x * 256 + threadIdx.x;
    if (row >= n) return;
    const float4* xr = (const float4*)(x + (size_t)row * F_IN);

    float acc[H_DIM];
#pragma unroll
    for (int j = 0; j < H_DIM; ++j) acc[j] = 0.f;

    for (int c = 0; c < F_IN / 16; ++c) {        // 32 chunks of 16 k (64B/lane)
        float4 xv0 = xr[c * 4 + 0];
        float4 xv1 = xr[c * 4 + 1];
        float4 xv2 = xr[c * 4 + 2];
        float4 xv3 = xr[c * 4 + 3];
        float xs[16] = {xv0.x, xv0.y, xv0.z, xv0.w,
                        xv1.x, xv1.y, xv1.z, xv1.w,
                        xv2.x, xv2.y, xv2.z, xv2.w,
                        xv3.x, xv3.y, xv3.z, xv3.w};
#pragma unroll
        for (int kk = 0; kk < 16; ++kk) {
            const float* wr = &Ws[(c * 16 + kk) * H_DIM];
#pragma unroll
            for (int j = 0; j < H_DIM; ++j) acc[j] += xs[kk] * wr[j];
        }
    }

    float ns = rsqrtf(fmaxf((float)outdeg[row], 1.f));
    float4* o = (float4*)(h1 + (size_t)row * H_DIM);
#pragma unroll
    for (int qq = 0; qq < 4; ++qq)
        o[qq] = make_float4(acc[qq * 4 + 0] * ns, acc[qq * 4 + 1] * ns,
                            acc[qq * 4 + 2] * ns, acc[qq * 4 + 3] * ns);
}

// ---- agg1: g[v] = relu(norm_dst(v)*sum_{e in(v)} h1[src] + b1) * norm_src(v)
__global__ __launch_bounds__(256) void k_agg1(const int* __restrict__ csroff,
        const int* __restrict__ indeg, const int* __restrict__ outdeg,
        const int* __restrict__ csrsrc, const float* __restrict__ h1,
        const float* __restrict__ b1, float* __restrict__ g, int n) {
    int t = threadIdx.x;
    int q = t & 3;
    int lv = t >> 2;
    int v = blockIdx.x * 64 + lv;
    if (v >= n) return;
    int start = csroff[v];
    int len = indeg[v];
    const float4* h4 = (const float4*)h1;
    float4 acc = make_float4(0.f, 0.f, 0.f, 0.f);
    for (int i = 0; i < len; ++i) {
        int s = csrsrc[start + i];
        float4 m = h4[(size_t)s * 4 + q];
        acc.x += m.x; acc.y += m.y; acc.z += m.z; acc.w += m.w;
    }
    float nd = rsqrtf(fmaxf((float)len, 1.f));
    float ns = rsqrtf(fmaxf((float)outdeg[v], 1.f));
    float4 bb = ((const float4*)b1)[q];
    float4 r;
    r.x = fmaxf(acc.x * nd + bb.x, 0.f) * ns;
    r.y = fmaxf(acc.y * nd + bb.y, 0.f) * ns;
    r.z = fmaxf(acc.z * nd + bb.z, 0.f) * ns;
    r.w = fmaxf(acc.w * nd + bb.w, 0.f) * ns;
    ((float4*)g)[(size_t)v * 4 + q] = r;
}

// ---- agg2 + GEMM2: out[v] = norm_dst(v) * (sum g[src]) @ W2 + b2 -----------
__global__ __launch_bounds__(256) void k_agg2(const int* __restrict__ csroff,
        const int* __restrict__ indeg, const int* __restrict__ csrsrc,
        const float* __restrict__ gbuf, const float* __restrict__ W2,
        const float* __restrict__ b2, float* __restrict__ out, int n) {
    __shared__ float Ws[H_DIM * C_OUT];     // 2.56 KB
    __shared__ float agg[64][17];
    int t = threadIdx.x;
    for (int i = t; i < H_DIM * C_OUT; i += 256) Ws[i] = W2[i];

    int q = t & 3;
    int lv = t >> 2;
    int v = blockIdx.x * 64 + lv;
    float4 acc = make_float4(0.f, 0.f, 0.f, 0.f);
    if (v < n) {
        int start = csroff[v];
        int len = indeg[v];
        const float4* g4 = (const float4*)gbuf;
        for (int i = 0; i < len; ++i) {
            int s = csrsrc[start + i];
            float4 m = g4[(size_t)s * 4 + q];
            acc.x += m.x; acc.y += m.y; acc.z += m.z; acc.w += m.w;
        }
    }
    agg[lv][q * 4 + 0] = acc.x;
    agg[lv][q * 4 + 1] = acc.y;
    agg[lv][q * 4 + 2] = acc.z;
    agg[lv][q * 4 + 3] = acc.w;
    __syncthreads();

    for (int idx = t; idx < 64 * C_OUT; idx += 256) {
        int dlv = idx / C_OUT;
        int c = idx % C_OUT;
        int dv = blockIdx.x * 64 + dlv;
        if (dv < n) {
            float s = 0.f;
#pragma unroll
            for (int k = 0; k < H_DIM; ++k) s += agg[dlv][k] * Ws[k * C_OUT + c];
            float nd = rsqrtf(fmaxf((float)indeg[dv], 1.f));
            out[(size_t)dv * C_OUT + c] = s * nd + b2[c];
        }
    }
}

extern "C" void kernel_launch(void* const* d_in, const int* in_sizes, int n_in,
                              void* d_out, int out_size, void* d_ws, size_t ws_size,
                              hipStream_t stream) {
    const float* x  = (const float*)d_in[0];
    const int* esrc = (const int*)d_in[1];
    const int* edst = (const int*)d_in[2];
    const float* W1 = (const float*)d_in[3];
    const float* b1 = (const float*)d_in[4];
    const float* W2 = (const float*)d_in[5];
    const float* b2 = (const float*)d_in[6];
    float* out = (float*)d_out;

    const int N = in_sizes[0] / F_IN;   // 100000
    const int E = in_sizes[1];          // 3200000
    const int nbk = (N + 255) >> 8;     // 391 buckets of 256 nodes
    const int n2 = nbk * NBLK_P;        // scan length (100096)
    const int chunk = (E + NBLK_P - 1) / NBLK_P;

    char* p = (char*)d_ws;
    auto alloc = [&](size_t bytes) -> char* {
        char* r = p; p += align_up(bytes, 256); return r;
    };
    int*  histS  = (int*)alloc((size_t)n2 * 4);        // 400 KB
    int*  histT  = (int*)alloc((size_t)n2 * 4);        // 400 KB
    int*  bsums  = (int*)alloc(512 * 4);
    int2* pairsb = (int2*)alloc((size_t)E * 8);        // 25.6 MB (reused: h1,g)
    int*  srcb   = (int*)alloc((size_t)E * 4);         // 12.8 MB (reused: csrsrc)
    int*  indeg  = (int*)alloc((size_t)N * 4);
    int*  outdeg = (int*)alloc((size_t)N * 4);
    int*  csroff = (int*)alloc((size_t)N * 4);

    // aliases (dead-buffer reuse, stream-ordered):
    int*   csrsrc = srcb;                // srcb dead after k_bcount
    float* h1     = (float*)pairsb;      // pairsb dead after k_bbuild
    float* g      = h1 + (size_t)N * H_DIM;

    int nbs = (n2 + 255) / 256;          // = nbk

    // ---- outdeg: partition src by src>>8, per-bucket count ----
    k_pcount<<<NBLK_P, 256, 0, stream>>>(esrc, E, chunk, nbk, histS);
    k_scan1<<<nbs, 256, 0, stream>>>(histS, histS, bsums, n2);
    k_scan2<<<1, 512, 0, stream>>>(bsums, nbs);
    k_scan3<<<nbs, 256, 0, stream>>>(histS, bsums, n2);
    k_pscat_key<<<NBLK_P, 256, 0, stream>>>(esrc, E, chunk, histS, srcb);
    k_bcount<<<nbk, 256, 0, stream>>>(srcb, histS, nbk, E, N, outdeg);

    // ---- CSR by dst: partition (src,dst) by dst>>8, per-bucket build ----
    k_pcount<<<NBLK_P, 256, 0, stream>>>(edst, E, chunk, nbk, histT);
    k_scan1<<<nbs, 256, 0, stream>>>(histT, histT, bsums, n2);
    k_scan2<<<1, 512, 0, stream>>>(bsums, nbs);
    k_scan3<<<nbs, 256, 0, stream>>>(histT, bsums, n2);
    k_pscat_pair<<<NBLK_P, 256, 0, stream>>>(esrc, edst, E, chunk, histT, pairsb);
    k_bbuild<<<nbk, 256, 0, stream>>>(pairsb, histT, nbk, E, N, indeg, csroff, csrsrc);

    // ---- dense pipeline ----
    k_gemm1<<<(N + 255) / 256, 256, 0, stream>>>(x, W1, outdeg, h1, N);
    int nb64 = (N + 63) / 64;
    k_agg1<<<nb64, 256, 0, stream>>>(csroff, indeg, outdeg, csrsrc, h1, b1, g, N);
    k_agg2<<<nb64, 256, 0, stream>>>(csroff, indeg, csrsrc, g, W2, b2, out, N);
}

// Round 3
// 279.586 us; speedup vs baseline: 2.2226x; 1.1308x over previous
//
#include <hip/hip_runtime.h>

#define F_IN  512
#define H_DIM 16
#define C_OUT 40
#define NBLK_P 256          // partition blocks

static inline size_t align_up(size_t x, size_t a) { return (x + a - 1) / a * a; }

// ---- phase A: per-block LDS histograms of src>>8 AND dst>>8 (one pass) -----
__global__ __launch_bounds__(256) void k_pcount(const int* __restrict__ src,
        const int* __restrict__ dst, int E, int chunk, int nbk,
        int* __restrict__ histS, int* __restrict__ histT) {
    __shared__ int hs[512], hd[512];
    for (int i = threadIdx.x; i < 512; i += 256) { hs[i] = 0; hd[i] = 0; }
    __syncthreads();
    int b = blockIdx.x;
    int s = b * chunk, e = min(s + chunk, E);
    for (int i = s + threadIdx.x; i < e; i += 256) {
        atomicAdd(&hs[src[i] >> 8], 1);
        atomicAdd(&hd[dst[i] >> 8], 1);
    }
    __syncthreads();
    for (int i = threadIdx.x; i < nbk; i += 256) {
        histS[i * NBLK_P + b] = hs[i];
        histT[i * NBLK_P + b] = hd[i];
    }
}

// ---- 2-level exclusive scan over both histograms (gridDim.y = 2) -----------
__global__ void k_scan1(int* __restrict__ histS, int* __restrict__ histT,
                        int* __restrict__ bsums) {
    __shared__ int tmp[256];
    int* h = blockIdx.y ? histT : histS;
    int* bs = bsums + blockIdx.y * 512;
    int t = threadIdx.x;
    int gid = blockIdx.x * 256 + t;
    int v = h[gid];
    tmp[t] = v;
    __syncthreads();
    for (int off = 1; off < 256; off <<= 1) {
        int add = (t >= off) ? tmp[t - off] : 0;
        __syncthreads();
        tmp[t] += add;
        __syncthreads();
    }
    h[gid] = tmp[t] - v;                  // exclusive (within block)
    if (t == 255) bs[blockIdx.x] = tmp[255];
}

__global__ void k_scan2(int* __restrict__ bsums, int nb) {
    __shared__ int tmp[512];
    int* bs = bsums + blockIdx.x * 512;
    int t = threadIdx.x;
    int v = (t < nb) ? bs[t] : 0;
    tmp[t] = v;
    __syncthreads();
    for (int off = 1; off < 512; off <<= 1) {
        int add = (t >= off) ? tmp[t - off] : 0;
        __syncthreads();
        tmp[t] += add;
        __syncthreads();
    }
    if (t < nb) bs[t] = tmp[t] - v;       // exclusive block offsets
}

__global__ void k_scan3(int* __restrict__ histS, int* __restrict__ histT,
                        const int* __restrict__ bsums) {
    int* h = blockIdx.y ? histT : histS;
    const int* bs = bsums + blockIdx.y * 512;
    h[blockIdx.x * 256 + threadIdx.x] += bs[blockIdx.x];
}

// ---- phase C: fused dual scatter (src low-byte; packed (src,dst&255)) ------
__global__ __launch_bounds__(256) void k_pscat(const int* __restrict__ src,
        const int* __restrict__ dst, int E, int chunk,
        const int* __restrict__ histS, const int* __restrict__ histT,
        unsigned char* __restrict__ srcb, unsigned int* __restrict__ pairsb) {
    __shared__ int cs[512], cd[512];
    for (int i = threadIdx.x; i < 512; i += 256) { cs[i] = 0; cd[i] = 0; }
    __syncthreads();
    int b = blockIdx.x;
    int s = b * chunk, e = min(s + chunk, E);
    for (int i = s + threadIdx.x; i < e; i += 256) {
        int k = src[i];
        int d = dst[i];
        int bks = k >> 8;
        int bkd = d >> 8;
        int rs = atomicAdd(&cs[bks], 1);
        int rd = atomicAdd(&cd[bkd], 1);
        srcb[histS[bks * NBLK_P + b] + rs] = (unsigned char)(k & 255);
        pairsb[histT[bkd * NBLK_P + b] + rd] =
            (unsigned int)k | ((unsigned int)(d & 255) << 24);
    }
}

// ---- per-bucket: outdeg count + CSR build (no global atomics) --------------
__global__ __launch_bounds__(256) void k_bbuild(const unsigned char* __restrict__ srcb,
        const unsigned int* __restrict__ pairsb,
        const int* __restrict__ histS, const int* __restrict__ histT,
        int nbk, int E, int N, int* __restrict__ outdeg,
        int* __restrict__ indeg, int* __restrict__ csroff, int* __restrict__ csrsrc) {
    __shared__ int h[256], offs[256], cnt[256], tmp[256];
    int t = threadIdx.x, b = blockIdx.x;
    int node = (b << 8) + t;

    // phase A: out-degree from bucketed src bytes
    int sstart = histS[b * NBLK_P];
    int send = (b + 1 < nbk) ? histS[(b + 1) * NBLK_P] : E;
    h[t] = 0;
    __syncthreads();
    for (int i = sstart + t; i < send; i += 256)
        atomicAdd(&h[srcb[i]], 1);
    __syncthreads();
    if (node < N) outdeg[node] = h[t];
    __syncthreads();

    // phase B: in-degree + CSR from packed pairs
    int bstart = histT[b * NBLK_P];
    int bend = (b + 1 < nbk) ? histT[(b + 1) * NBLK_P] : E;
    h[t] = 0; cnt[t] = 0;
    __syncthreads();
    for (int i = bstart + t; i < bend; i += 256)
        atomicAdd(&h[pairsb[i] >> 24], 1);
    __syncthreads();
    int v = h[t];
    tmp[t] = v;
    __syncthreads();
    for (int off = 1; off < 256; off <<= 1) {
        int add = (t >= off) ? tmp[t - off] : 0;
        __syncthreads();
        tmp[t] += add;
        __syncthreads();
    }
    offs[t] = tmp[t] - v;
    __syncthreads();
    if (node < N) {
        indeg[node] = v;
        csroff[node] = bstart + offs[t];
    }
    for (int i = bstart + t; i < bend; i += 256) {
        unsigned int p = pairsb[i];
        int l = p >> 24;
        int r = atomicAdd(&cnt[l], 1);
        csrsrc[bstart + offs[l] + r] = (int)(p & 0xFFFFFF);
    }
}

// ---- GEMM1: h1[row] = norm_src(row) * (x[row] @ W1) ------------------------
__global__ __launch_bounds__(256) void k_gemm1(const float* __restrict__ x,
        const float* __restrict__ W1, const int* __restrict__ outdeg,
        float* __restrict__ h1, int n) {
    __shared__ float Ws[F_IN * H_DIM];           // 32 KB
    for (int i = threadIdx.x; i < F_IN * H_DIM / 4; i += 256)
        ((float4*)Ws)[i] = ((const float4*)W1)[i];
    __syncthreads();

    int row = blockIdx.x * 256 + threadIdx.x;
    if (row >= n) return;
    const float4* xr = (const float4*)(x + (size_t)row * F_IN);
    float ns = rsqrtf(fmaxf((float)outdeg[row], 1.f));

    float acc[H_DIM];
#pragma unroll
    for (int j = 0; j < H_DIM; ++j) acc[j] = 0.f;

    for (int c = 0; c < F_IN / 16; ++c) {        // 32 chunks of 16 k (64B/lane)
        float4 xv0 = xr[c * 4 + 0];
        float4 xv1 = xr[c * 4 + 1];
        float4 xv2 = xr[c * 4 + 2];
        float4 xv3 = xr[c * 4 + 3];
        float xs[16] = {xv0.x, xv0.y, xv0.z, xv0.w,
                        xv1.x, xv1.y, xv1.z, xv1.w,
                        xv2.x, xv2.y, xv2.z, xv2.w,
                        xv3.x, xv3.y, xv3.z, xv3.w};
#pragma unroll
        for (int kk = 0; kk < 16; ++kk) {
            const float* wr = &Ws[(c * 16 + kk) * H_DIM];
#pragma unroll
            for (int j = 0; j < H_DIM; ++j) acc[j] += xs[kk] * wr[j];
        }
    }

    float4* o = (float4*)(h1 + (size_t)row * H_DIM);
#pragma unroll
    for (int qq = 0; qq < 4; ++qq)
        o[qq] = make_float4(acc[qq * 4 + 0] * ns, acc[qq * 4 + 1] * ns,
                            acc[qq * 4 + 2] * ns, acc[qq * 4 + 3] * ns);
}

// ---- agg1: g[v] = relu(norm_dst(v)*sum h1[src] + b1) * norm_src(v) ---------
__global__ __launch_bounds__(256) void k_agg1(const int* __restrict__ csroff,
        const int* __restrict__ indeg, const int* __restrict__ outdeg,
        const int* __restrict__ csrsrc, const float* __restrict__ h1,
        const float* __restrict__ b1, float* __restrict__ g, int n) {
    int t = threadIdx.x;
    int q = t & 3;
    int lv = t >> 2;
    int v = blockIdx.x * 64 + lv;
    if (v >= n) return;
    int start = csroff[v];
    int len = indeg[v];
    const float4* h4 = (const float4*)h1;
    float4 acc = make_float4(0.f, 0.f, 0.f, 0.f);
    int i = 0;
    for (; i + 4 <= len; i += 4) {               // 4 gathers in flight
        int s0 = csrsrc[start + i + 0];
        int s1 = csrsrc[start + i + 1];
        int s2 = csrsrc[start + i + 2];
        int s3 = csrsrc[start + i + 3];
        float4 m0 = h4[(size_t)s0 * 4 + q];
        float4 m1 = h4[(size_t)s1 * 4 + q];
        float4 m2 = h4[(size_t)s2 * 4 + q];
        float4 m3 = h4[(size_t)s3 * 4 + q];
        acc.x += m0.x + m1.x + m2.x + m3.x;
        acc.y += m0.y + m1.y + m2.y + m3.y;
        acc.z += m0.z + m1.z + m2.z + m3.z;
        acc.w += m0.w + m1.w + m2.w + m3.w;
    }
    for (; i < len; ++i) {
        int s = csrsrc[start + i];
        float4 m = h4[(size_t)s * 4 + q];
        acc.x += m.x; acc.y += m.y; acc.z += m.z; acc.w += m.w;
    }
    float nd = rsqrtf(fmaxf((float)len, 1.f));
    float ns = rsqrtf(fmaxf((float)outdeg[v], 1.f));
    float4 bb = ((const float4*)b1)[q];
    float4 r;
    r.x = fmaxf(acc.x * nd + bb.x, 0.f) * ns;
    r.y = fmaxf(acc.y * nd + bb.y, 0.f) * ns;
    r.z = fmaxf(acc.z * nd + bb.z, 0.f) * ns;
    r.w = fmaxf(acc.w * nd + bb.w, 0.f) * ns;
    ((float4*)g)[(size_t)v * 4 + q] = r;
}

// ---- agg2 + GEMM2: out[v] = norm_dst(v) * (sum g[src]) @ W2 + b2 -----------
__global__ __launch_bounds__(256) void k_agg2(const int* __restrict__ csroff,
        const int* __restrict__ indeg, const int* __restrict__ csrsrc,
        const float* __restrict__ gbuf, const float* __restrict__ W2,
        const float* __restrict__ b2, float* __restrict__ out, int n) {
    __shared__ float Ws[H_DIM * C_OUT];     // 2.56 KB
    __shared__ float agg[64][17];
    int t = threadIdx.x;
    for (int i = t; i < H_DIM * C_OUT; i += 256) Ws[i] = W2[i];

    int q = t & 3;
    int lv = t >> 2;
    int v = blockIdx.x * 64 + lv;
    float4 acc = make_float4(0.f, 0.f, 0.f, 0.f);
    if (v < n) {
        int start = csroff[v];
        int len = indeg[v];
        const float4* g4 = (const float4*)gbuf;
        int i = 0;
        for (; i + 4 <= len; i += 4) {
            int s0 = csrsrc[start + i + 0];
            int s1 = csrsrc[start + i + 1];
            int s2 = csrsrc[start + i + 2];
            int s3 = csrsrc[start + i + 3];
            float4 m0 = g4[(size_t)s0 * 4 + q];
            float4 m1 = g4[(size_t)s1 * 4 + q];
            float4 m2 = g4[(size_t)s2 * 4 + q];
            float4 m3 = g4[(size_t)s3 * 4 + q];
            acc.x += m0.x + m1.x + m2.x + m3.x;
            acc.y += m0.y + m1.y + m2.y + m3.y;
            acc.z += m0.z + m1.z + m2.z + m3.z;
            acc.w += m0.w + m1.w + m2.w + m3.w;
        }
        for (; i < len; ++i) {
            int s = csrsrc[start + i];
            float4 m = g4[(size_t)s * 4 + q];
            acc.x += m.x; acc.y += m.y; acc.z += m.z; acc.w += m.w;
        }
    }
    agg[lv][q * 4 + 0] = acc.x;
    agg[lv][q * 4 + 1] = acc.y;
    agg[lv][q * 4 + 2] = acc.z;
    agg[lv][q * 4 + 3] = acc.w;
    __syncthreads();

    for (int idx = t; idx < 64 * C_OUT; idx += 256) {
        int dlv = idx / C_OUT;
        int c = idx % C_OUT;
        int dv = blockIdx.x * 64 + dlv;
        if (dv < n) {
            float s = 0.f;
#pragma unroll
            for (int k = 0; k < H_DIM; ++k) s += agg[dlv][k] * Ws[k * C_OUT + c];
            float nd = rsqrtf(fmaxf((float)indeg[dv], 1.f));
            out[(size_t)dv * C_OUT + c] = s * nd + b2[c];
        }
    }
}

extern "C" void kernel_launch(void* const* d_in, const int* in_sizes, int n_in,
                              void* d_out, int out_size, void* d_ws, size_t ws_size,
                              hipStream_t stream) {
    const float* x  = (const float*)d_in[0];
    const int* esrc = (const int*)d_in[1];
    const int* edst = (const int*)d_in[2];
    const float* W1 = (const float*)d_in[3];
    const float* b1 = (const float*)d_in[4];
    const float* W2 = (const float*)d_in[5];
    const float* b2 = (const float*)d_in[6];
    float* out = (float*)d_out;

    const int N = in_sizes[0] / F_IN;   // 100000
    const int E = in_sizes[1];          // 3200000
    const int nbk = (N + 255) >> 8;     // 391 buckets of 256 nodes
    const int chunk = (E + NBLK_P - 1) / NBLK_P;

    char* p = (char*)d_ws;
    auto alloc = [&](size_t bytes) -> char* {
        char* r = p; p += align_up(bytes, 256); return r;
    };
    int*  histS  = (int*)alloc((size_t)nbk * NBLK_P * 4);   // 400 KB
    int*  histT  = (int*)alloc((size_t)nbk * NBLK_P * 4);   // 400 KB
    int*  bsums  = (int*)alloc(1024 * 4);
    unsigned int*  pairsb = (unsigned int*)alloc((size_t)E * 4);  // 12.8 MB (→ h1,g)
    unsigned char* srcb   = (unsigned char*)alloc((size_t)E);     // 3.2 MB
    int*  csrsrc = (int*)alloc((size_t)E * 4);              // 12.8 MB
    int*  indeg  = (int*)alloc((size_t)N * 4);
    int*  outdeg = (int*)alloc((size_t)N * 4);
    int*  csroff = (int*)alloc((size_t)N * 4);

    // alias: pairsb dead after k_bbuild; h1+g = 2*N*16*4 = 12.8 MB fits exactly
    float* h1 = (float*)pairsb;
    float* g  = h1 + (size_t)N * H_DIM;

    k_pcount<<<NBLK_P, 256, 0, stream>>>(esrc, edst, E, chunk, nbk, histS, histT);
    k_scan1<<<dim3(nbk, 2), 256, 0, stream>>>(histS, histT, bsums);
    k_scan2<<<2, 512, 0, stream>>>(bsums, nbk);
    k_scan3<<<dim3(nbk, 2), 256, 0, stream>>>(histS, histT, bsums);
    k_pscat<<<NBLK_P, 256, 0, stream>>>(esrc, edst, E, chunk, histS, histT,
                                        srcb, pairsb);
    k_bbuild<<<nbk, 256, 0, stream>>>(srcb, pairsb, histS, histT, nbk, E, N,
                                      outdeg, indeg, csroff, csrsrc);

    k_gemm1<<<(N + 255) / 256, 256, 0, stream>>>(x, W1, outdeg, h1, N);
    int nb64 = (N + 63) / 64;
    k_agg1<<<nb64, 256, 0, stream>>>(csroff, indeg, outdeg, csrsrc, h1, b1, g, N);
    k_agg2<<<nb64, 256, 0, stream>>>(csroff, indeg, csrsrc, g, W2, b2, out, N);
}